// Round 8
// baseline (313.069 us; speedup 1.0000x reference)
//
#include <hip/hip_runtime.h>
#include <math.h>

#define BB_ 2
#define C0 6
#define S0 48
#define V0 (S0*S0*S0)      // 110592
#define C1 192
#define S1 24
#define V1 (S1*S1*S1)      // 13824
#define C2 768
#define S2 12
#define LL (S2*S2*S2)      // 1728
#define NH 12
#define HD 64
#define KDIM (C1*8)        // 1536
#define MDIM (BB_*LL)      // 3456

typedef __attribute__((ext_vector_type(8))) short short8;
typedef __attribute__((ext_vector_type(4))) short short4v;
typedef __attribute__((ext_vector_type(4))) float float4v;

static __device__ __forceinline__ float gelu_exact(float x){
  return 0.5f*x*(1.0f+erff(x*0.70710678118654752440f));
}
static __device__ __forceinline__ unsigned short f2bf(float f){
  unsigned int u = __float_as_uint(f);
  unsigned int r = (u + 0x7fffu + ((u>>16)&1u)) >> 16;
  return (unsigned short)r;
}
static __device__ __forceinline__ unsigned int pk_bf16(float a, float b){
#if __has_builtin(__builtin_amdgcn_cvt_pk_bf16_f32)
  typedef __attribute__((ext_vector_type(2))) __bf16 bf2;
  bf2 r = __builtin_amdgcn_cvt_pk_bf16_f32(a,b);
  union { bf2 v; unsigned int u; } cv; cv.v = r;
  return cv.u;
#else
  return (unsigned int)f2bf(a) | ((unsigned int)f2bf(b)<<16);
#endif
}
static __device__ __forceinline__ float bf2f(unsigned short u){
  return __uint_as_float(((unsigned int)u)<<16);
}
static __device__ __forceinline__ float exp2v(float x){
#if __has_builtin(__builtin_amdgcn_exp2f)
  return __builtin_amdgcn_exp2f(x);
#else
  return exp2f(x);
#endif
}
static __device__ __forceinline__ void load_lds16(const void* g, void* l){
  __builtin_amdgcn_global_load_lds((const __attribute__((address_space(1))) unsigned int*)g,
      (__attribute__((address_space(3))) unsigned int*)l, 16, 0, 0);
}
static __device__ __forceinline__ float4v mfma32(short8 a, short8 b, float4v c){
  return __builtin_amdgcn_mfma_f32_16x16x32_bf16(a,b,c,0,0,0);
}
static __device__ __forceinline__ float4v mfma16(short4v a, short4v b, float4v c){
#if __has_builtin(__builtin_amdgcn_mfma_f32_16x16x16bf16_1k)
  return __builtin_amdgcn_mfma_f32_16x16x16bf16_1k(a,b,c,0,0,0);
#else
  asm volatile("v_mfma_f32_16x16x16_bf16 %0, %1, %2, %0" : "+v"(c) : "v"(a), "v"(b));
  return c;
#endif
}

// A matrices for the big GEMMs are stored K-BLOCKED: [m/128][k/32][128][32] (8KB tiles)
// B matrices: [n/64][k/32][64][32] (4KB tiles) -> staging reads are CONTIGUOUS (DRAM-friendly).

// ---------------- prep: LN6 (skip,x) + all weight repacks, one launch ----------------
__global__ __launch_bounds__(256) void prep_kernel(
    const float* __restrict__ skin, const float* __restrict__ xin,
    const float* __restrict__ nsw, const float* __restrict__ nsb,
    const float* __restrict__ nxw, const float* __restrict__ nxb,
    unsigned short* __restrict__ outS, unsigned short* __restrict__ outX,
    const float* __restrict__ qw2, const float* __restrict__ kw2, const float* __restrict__ vw2,
    const float* __restrict__ tw1, const float* __restrict__ tw2,
    const float* __restrict__ qw1, const float* __restrict__ kw1, const float* __restrict__ vw1,
    unsigned short* __restrict__ w2tq, unsigned short* __restrict__ w2tk,
    unsigned short* __restrict__ w2tv, unsigned short* __restrict__ Btd,
    unsigned short* __restrict__ Bt48,
    unsigned short* __restrict__ w1q, unsigned short* __restrict__ w1k,
    unsigned short* __restrict__ w1v){
  int bx = blockIdx.x;
  if (bx < 1728){                         // LN over 6 channels (channels_first)
    int z = bx >= 864;
    const float* in = z ? xin : skin;
    const float* w  = z ? nxw : nsw;
    const float* bi = z ? nxb : nsb;
    unsigned short* out = z ? outX : outS;
    int idx = (bx - z*864)*256 + threadIdx.x;
    int b = idx / V0, vox = idx - b*V0;
    const float* p = in + (size_t)b*(C0*V0) + vox;
    float v[C0]; float s=0.f;
#pragma unroll
    for (int c=0;c<C0;c++){ v[c]=p[(size_t)c*V0]; s+=v[c]; }
    float u = s*(1.f/C0);
    float ss=0.f;
#pragma unroll
    for (int c=0;c<C0;c++){ float d=v[c]-u; ss+=d*d; }
    float inv = rsqrtf(ss*(1.f/C0)+1e-6f);
    unsigned short* o = out + (size_t)b*(C0*V0) + vox;
#pragma unroll
    for (int c=0;c<C0;c++) o[(size_t)c*V0] = f2bf((v[c]-u)*inv*w[c]+bi[c]);
    return;
  }
  bx -= 1728;
  if (bx < 13824){                       // 3 x 4608 : w2 repacks -> blocked [oc/64][k/32][64][32]
    int z = bx/4608;
    int idx = (bx - z*4608)*256 + threadIdx.x;
    const float* w2 = (z==0)?qw2:((z==1)?kw2:vw2);
    unsigned short* o = (z==0)?w2tq:((z==1)?w2tk:w2tv);
    int oc = idx/KDIM; int k = idx-oc*KDIM; int p = k/C1; int ic = k-p*C1;
    size_t dst = ((size_t)(oc>>6)*48 + (k>>5))*2048 + (oc&63)*32 + (k&31);
    o[dst] = f2bf(w2[(size_t)oc*KDIM + ic*8 + p]);
  } else if (bx < 18432){                // tw1 -> blocked [n/64][k/32][64][32] (k=p head-major)
    int idx = (bx-13824)*256 + threadIdx.x;
    int n = idx/C2; int p = idx-n*C2;
    int i = ((p&63)*NH) + (p>>6);
    int kpq = n/C1, o2 = n-kpq*C1;
    size_t dst = ((size_t)(n>>6)*24 + (p>>5))*2048 + (n&63)*32 + (p&31);
    Btd[dst] = f2bf(tw1[(size_t)i*KDIM + o2*8 + kpq]);
  } else if (bx < 18480){                // 48 blocks: tw2 -> [n=c*8+kpq pad64][i]
    int idx = (bx-18432)*256 + threadIdx.x;
    int n = idx/C1; int i = idx-n*C1;
    Bt48[idx] = (n<48) ? f2bf(tw2[(size_t)i*48 + n]) : (unsigned short)0;
  } else {                               // 108 blocks: w1 -> bf16 passthrough
    int idx = (bx-18480)*256 + threadIdx.x;  // 27648 = 3*9216
    int z = idx / 9216; int r = idx - z*9216;
    const float* w1 = (z==0)?qw1:((z==1)?kw1:vw1);
    unsigned short* o = (z==0)?w1q:((z==1)?w1k:w1v);
    o[r] = f2bf(w1[r]);
  }
}

// ------------- conv1 via MFMA, one tile-job per wave; blocked output via LDS transpose -------------
__global__ __launch_bounds__(256) void conv1_kernel(
    const unsigned short* __restrict__ lnSb, const unsigned short* __restrict__ lnXb,
    const unsigned short* __restrict__ w1bq, const unsigned short* __restrict__ w1bk,
    const unsigned short* __restrict__ w1bv,
    const float* __restrict__ qg1, const float* __restrict__ qb1,
    const float* __restrict__ kg1, const float* __restrict__ kb1,
    const float* __restrict__ vg1, const float* __restrict__ vb1,
    unsigned short* __restrict__ h1q, unsigned short* __restrict__ h1k,
    unsigned short* __restrict__ h1v){
  __shared__ __align__(16) unsigned short Ost[4][16*200];   // 25.6 KB, padded vs bank conflict
  int z = blockIdx.z;
  const unsigned short* in = (z==0)? lnSb : lnXb;
  const unsigned short* Wb = (z==0)?w1bq:((z==1)?w1bk:w1bv);
  const float* g1 = (z==0)?qg1:((z==1)?kg1:vg1);
  const float* b1 = (z==0)?qb1:((z==1)?kb1:vb1);
  unsigned short* h1p = (z==0)?h1q:((z==1)?h1k:h1v);
  int t = threadIdx.x, w = t>>6, lane = t&63;
  int g = lane>>4, l16 = lane&15;
  int j = blockIdx.x*4 + w;
  int bxh = j/18, mt = j - bxh*18;
  int b = bxh/48; int rem = bxh - b*48; int y = rem>>1, xh = rem&1;
  int xo = mt/3, zo = mt - xo*3;
  int xv = xh*12 + xo*2 + (l16>>3);
  int zv = zo*8 + (l16&7);
  int x2 = 2*xv, z2 = 2*zv, y2 = 2*y;
  const unsigned short* base = in + (size_t)b*C0*V0;
  union { short8 v; unsigned int u[4]; } aA;     // k=g*8+jj  -> ic=g, p=jj
  {
    size_t rb = (size_t)g*V0;
    aA.u[0] = *(const unsigned int*)&base[rb + (y2+0)*(S0*S0) + (x2+0)*S0 + z2];
    aA.u[1] = *(const unsigned int*)&base[rb + (y2+0)*(S0*S0) + (x2+1)*S0 + z2];
    aA.u[2] = *(const unsigned int*)&base[rb + (y2+1)*(S0*S0) + (x2+0)*S0 + z2];
    aA.u[3] = *(const unsigned int*)&base[rb + (y2+1)*(S0*S0) + (x2+1)*S0 + z2];
  }
  union { short4v v; unsigned int u[2]; } aB;    // k=32+g*4+jj -> ic=4+(g>>1), p=(g&1)*4+jj
  {
    size_t rb = (size_t)(4+(g>>1))*V0 + (y2+(g&1))*(S0*S0);
    aB.u[0] = *(const unsigned int*)&base[rb + (x2+0)*S0 + z2];
    aB.u[1] = *(const unsigned int*)&base[rb + (x2+1)*S0 + z2];
  }
  float4v acc[12];
#pragma unroll
  for (int ot=0; ot<12; ot++){
    short8  wA = *(const short8*)&Wb[(ot*16+l16)*48 + g*8];
    short4v wB = *(const short4v*)&Wb[(ot*16+l16)*48 + 32 + g*4];
    float4v a = {};
    a = mfma32(wA, aA.v, a);
    a = mfma16(wB, aB.v, a);
    acc[ot] = a;
  }
  float s1=0.f, s2=0.f;
#pragma unroll
  for (int ot=0;ot<12;ot++)
#pragma unroll
    for (int reg=0;reg<4;reg++){ float v=acc[ot][reg]; s1+=v; s2+=v*v; }
  s1 += __shfl_xor(s1,16); s1 += __shfl_xor(s1,32);
  s2 += __shfl_xor(s2,16); s2 += __shfl_xor(s2,32);
  float u = s1*(1.f/C1);
  float inv = rsqrtf(s2*(1.f/C1)-u*u+1e-6f);
  // token geometry: tok = tokbase + t2, t2=(l16&7)>>1 (4 consecutive, 4-aligned)
  int tokbase = (y>>1)*(S2*S2) + (xh*6+xo)*S2 + zo*4;
  int m0_ = b*LL + tokbase;
  int panel = m0_>>7, row0 = m0_&127;
  int Y4 = (y&1)*4;
  int p8x = (l16>>3)*2 + (l16&1);     // p8 = Y4 + p8x
  int t2 = (l16&7)>>1;
  unsigned short* Lw = &Ost[w][(p8x*4+t2)*200];
#pragma unroll
  for (int ot=0; ot<12; ot++){
    int oc0 = ot*16 + g*4;
    float4 gg = *(const float4*)&g1[oc0];
    float4 bb = *(const float4*)&b1[oc0];
    float x0 = gelu_exact((acc[ot][0]-u)*inv*gg.x+bb.x);
    float x1 = gelu_exact((acc[ot][1]-u)*inv*gg.y+bb.y);
    float x2e= gelu_exact((acc[ot][2]-u)*inv*gg.z+bb.z);
    float x3 = gelu_exact((acc[ot][3]-u)*inv*gg.w+bb.w);
    uint2 pk; pk.x = pk_bf16(x0,x1); pk.y = pk_bf16(x2e,x3);
    *(uint2*)&Lw[oc0] = pk;
  }
  __syncthreads();
  // write out: chunk c = p8x*6 + ocr (24 chunks/wave), each 4 rows x 32 k = 256B contiguous
  unsigned short* pb2 = h1p + ((size_t)panel*48 + Y4*6)*4096 + row0*32;
#pragma unroll
  for (int it=0; it<6; it++){
    int flat = it*64 + lane;
    int c = flat>>4, s = flat&15;          // c in 0..23, s in 0..15
    int pp = c/6, ocr = c - pp*6;
    uint4 d = *(const uint4*)&Ost[w][(pp*4 + (s>>2))*200 + ocr*32 + (s&3)*8];
    *(uint4*)&pb2[(size_t)c*4096 + (s>>2)*32 + (s&3)*8] = d;
  }
}

// ---------------- fused stem GEMM, 128x64 tiles, 3-ring counted vmcnt, CONTIGUOUS tiles ----------------
__global__ __launch_bounds__(256) void gemm_stem_kernel(
    const unsigned short* __restrict__ A0, const unsigned short* __restrict__ A1,
    const unsigned short* __restrict__ A2,
    const unsigned short* __restrict__ B0, const unsigned short* __restrict__ B1,
    const unsigned short* __restrict__ B2,
    unsigned short* __restrict__ Cq, unsigned short* __restrict__ Ck,
    unsigned short* __restrict__ Cv){
  int flat = blockIdx.x;
  int xcd = flat & 7, slot = flat >> 3;
  int tile = xcd*122 + slot;
  if (tile >= 972) return;
  int z = tile/324; int rr = tile - z*324;
  int mp = rr/12, np = rr - mp*12;
  const unsigned short* A = (z==0)?A0:((z==1)?A1:A2);
  const unsigned short* Bt = (z==0)?B0:((z==1)?B1:B2);
  unsigned short* Cp = (z==0)?Cq:((z==1)?Ck:Cv);
  __shared__ __align__(16) unsigned short Al[3][4096];
  __shared__ __align__(16) unsigned short Bl[3][2048];
  int t=threadIdx.x, w=t>>6, lane=t&63;
  int g=lane>>4, l16=lane&15;
  int wm=w>>1, wn=w&1;
  int loff = (lane>>2)*32 + (((lane&3) ^ ((lane>>3)&3))<<3);
  int crd  = (g ^ ((l16>>1)&3))*8;
  const unsigned short* gp[3];
  unsigned short* ld[3];
  int step[3];
#pragma unroll
  for (int cc=0;cc<3;cc++){
    int ch = w*3+cc;
    if (ch<8){
      gp[cc] = A + ((size_t)mp*48)*4096 + ch*512 + loff;
      step[cc] = 4096; ld[cc] = &Al[0][ch*512];
    } else {
      gp[cc] = Bt + ((size_t)np*48)*2048 + (ch-8)*512 + loff;
      step[cc] = 2048; ld[cc] = &Bl[0][(ch-8)*512];
    }
  }
  auto STAGE = [&](int buf){
#pragma unroll
    for (int cc=0;cc<3;cc++){
      load_lds16(gp[cc], ld[cc] + buf*step[cc]);
      gp[cc] += step[cc];
    }
  };
  float4v acc[4][2] = {};
  auto COMPUTE = [&](int buf){
    short8 af[4], bf[2];
#pragma unroll
    for (int mt=0;mt<4;mt++) af[mt] = *(const short8*)&Al[buf][(wm*64+mt*16+l16)*32 + crd];
#pragma unroll
    for (int nt=0;nt<2;nt++) bf[nt] = *(const short8*)&Bl[buf][(wn*32+nt*16+l16)*32 + crd];
#pragma unroll
    for (int mt=0;mt<4;mt++)
#pragma unroll
      for (int nt=0;nt<2;nt++)
        acc[mt][nt] = mfma32(af[mt], bf[nt], acc[mt][nt]);
  };
  const int NT = 48;
  STAGE(0); STAGE(1);
  asm volatile("s_waitcnt vmcnt(3)" ::: "memory");
  __builtin_amdgcn_s_barrier();
  __builtin_amdgcn_sched_barrier(0);
  int cur = 0;
  for (int tt=0; tt<NT-2; tt++){
    int nb = cur+2; if (nb>=3) nb-=3;
    STAGE(nb);
    COMPUTE(cur);
    asm volatile("s_waitcnt vmcnt(3)" ::: "memory");   // tile tt+1 landed; tt+2 in flight
    __builtin_amdgcn_s_barrier();
    __builtin_amdgcn_sched_barrier(0);
    cur++; if (cur>=3) cur-=3;
  }
  COMPUTE(cur);
  asm volatile("s_waitcnt vmcnt(0)" ::: "memory");
  __builtin_amdgcn_s_barrier();
  __builtin_amdgcn_sched_barrier(0);
  cur++; if (cur>=3) cur-=3;
  COMPUTE(cur);
  int m0 = mp*128, n0 = np*64;
#pragma unroll
  for (int mt=0;mt<4;mt++){
    int mb = m0 + wm*64 + mt*16 + g*4;
#pragma unroll
    for (int nt=0;nt<2;nt++){
      int col = n0 + wn*32 + nt*16 + l16;
#pragma unroll
      for (int reg=0;reg<4;reg++)
        Cp[(size_t)(mb+reg)*C2 + col] = f2bf(acc[mt][nt][reg]);
    }
  }
}

// ---------------- debed GEMM: 128x64 tiles, 3-ring counted vmcnt, CONTIGUOUS tiles ----------------
__global__ __launch_bounds__(256) void gemm_debed_kernel(const unsigned short* __restrict__ A,
    const unsigned short* __restrict__ Bt, unsigned short* __restrict__ C){
  int flat = blockIdx.x;
  int xcd = flat & 7, slot = flat >> 3;
  int tile = xcd*81 + slot;
  int mp = tile/24, np = tile - mp*24;
  __shared__ __align__(16) unsigned short Al[3][4096];
  __shared__ __align__(16) unsigned short Bl[3][2048];
  int t=threadIdx.x, w=t>>6, lane=t&63;
  int g=lane>>4, l16=lane&15;
  int wm=w>>1, wn=w&1;
  int loff = (lane>>2)*32 + (((lane&3) ^ ((lane>>3)&3))<<3);
  int crd  = (g ^ ((l16>>1)&3))*8;
  const unsigned short* gp[3];
  unsigned short* ld[3];
  int step[3];
#pragma unroll
  for (int cc=0;cc<3;cc++){
    int ch = w*3+cc;
    if (ch<8){
      gp[cc] = A + ((size_t)mp*24)*4096 + ch*512 + loff;
      step[cc] = 4096; ld[cc] = &Al[0][ch*512];
    } else {
      gp[cc] = Bt + ((size_t)np*24)*2048 + (ch-8)*512 + loff;
      step[cc] = 2048; ld[cc] = &Bl[0][(ch-8)*512];
    }
  }
  auto STAGE = [&](int buf){
#pragma unroll
    for (int cc=0;cc<3;cc++){
      load_lds16(gp[cc], ld[cc] + buf*step[cc]);
      gp[cc] += step[cc];
    }
  };
  float4v acc[4][2] = {};
  auto COMPUTE = [&](int buf){
    short8 af[4], bf[2];
#pragma unroll
    for (int mt=0;mt<4;mt++) af[mt] = *(const short8*)&Al[buf][(wm*64+mt*16+l16)*32 + crd];
#pragma unroll
    for (int nt=0;nt<2;nt++) bf[nt] = *(const short8*)&Bl[buf][(wn*32+nt*16+l16)*32 + crd];
#pragma unroll
    for (int mt=0;mt<4;mt++)
#pragma unroll
      for (int nt=0;nt<2;nt++)
        acc[mt][nt] = mfma32(af[mt], bf[nt], acc[mt][nt]);
  };
  const int NT = 24;
  STAGE(0); STAGE(1);
  asm volatile("s_waitcnt vmcnt(3)" ::: "memory");
  __builtin_amdgcn_s_barrier();
  __builtin_amdgcn_sched_barrier(0);
  int cur = 0;
  for (int tt=0; tt<NT-2; tt++){
    int nb = cur+2; if (nb>=3) nb-=3;
    STAGE(nb);
    COMPUTE(cur);
    asm volatile("s_waitcnt vmcnt(3)" ::: "memory");
    __builtin_amdgcn_s_barrier();
    __builtin_amdgcn_sched_barrier(0);
    cur++; if (cur>=3) cur-=3;
  }
  COMPUTE(cur);
  asm volatile("s_waitcnt vmcnt(0)" ::: "memory");
  __builtin_amdgcn_s_barrier();
  __builtin_amdgcn_sched_barrier(0);
  cur++; if (cur>=3) cur-=3;
  COMPUTE(cur);
  int m0 = mp*128, n0 = np*64;
#pragma unroll
  for (int nt=0;nt<2;nt++){
    int n = n0 + wn*32 + nt*16 + l16;
    int kpq = n / C1;
    int o = n - kpq*C1;
#pragma unroll
    for (int mt=0;mt<4;mt++){
      int mb = m0 + wm*64 + mt*16 + g*4;
#pragma unroll
      for (int reg=0;reg<4;reg++){
        int m = mb + reg;
        int b = m / LL; int tok = m - b*LL;
        int h = tok/(S2*S2), ww=(tok/S2)%S2, d=tok%S2;
        int v24 = (2*h+((kpq>>2)&1))*(S1*S1) + (2*ww+((kpq>>1)&1))*S1 + (2*d+(kpq&1));
        C[(size_t)(b*V1+v24)*C1 + o] = f2bf(acc[mt][nt][reg]);
      }
    }
  }
}

// ---------------- final: LN(192)+GELU fused into convT2 GEMM + bias + residual ----------------
__global__ __launch_bounds__(256) void final_kernel(const unsigned short* __restrict__ dh,
    const unsigned short* __restrict__ Bt48, const float* __restrict__ og,
    const float* __restrict__ ob, const float* __restrict__ tb2s,
    const float* __restrict__ skipp, float* __restrict__ out){
  __shared__ __align__(16) unsigned short As[64*200];
  __shared__ __align__(16) unsigned short Bs[64*200];
  int t=threadIdx.x, w=t>>6, lane=t&63;
  int g=lane>>4, l16=lane&15;
  int m0 = blockIdx.x*64;
  for (int n8 = t; n8 < 1536; n8 += 256){
    int n64 = n8/24, kk = (n8 - n64*24)*8;
    uint4 d4 = *(const uint4*)&Bt48[n64*192 + kk];
    *(uint4*)&Bs[n64*200 + kk] = d4;
  }
  float g0=og[lane], g1v=og[lane+64], g2v=og[lane+128];
  float b0=ob[lane], b1v=ob[lane+64], b2v=ob[lane+128];
  for (int rr=0; rr<16; rr++){
    int rl = w*16 + rr;
    const unsigned short* row = dh + (size_t)(m0+rl)*C1;
    float v0=bf2f(row[lane]), v1=bf2f(row[lane+64]), v2=bf2f(row[lane+128]);
    float s1=v0+v1+v2, s2=v0*v0+v1*v1+v2*v2;
#pragma unroll
    for (int off=32;off>0;off>>=1){ s1+=__shfl_xor(s1,off); s2+=__shfl_xor(s2,off); }
    float u=s1*(1.f/C1), inv=rsqrtf(s2*(1.f/C1)-u*u+1e-6f);
    As[rl*200+lane]     = f2bf(gelu_exact((v0-u)*inv*g0+b0));
    As[rl*200+lane+64]  = f2bf(gelu_exact((v1-u)*inv*g1v+b1v));
    As[rl*200+lane+128] = f2bf(gelu_exact((v2-u)*inv*g2v+b2v));
  }
  __syncthreads();
  int wm=w>>1, wn=w&1;
  float4v acc[2][2] = {};
#pragma unroll
  for (int kb=0;kb<192;kb+=32){
    short8 af[2], bf[2];
#pragma unroll
    for (int mt=0;mt<2;mt++) af[mt] = *(const short8*)&As[(wm*32+mt*16+l16)*200 + kb + g*8];
#pragma unroll
    for (int nt=0;nt<2;nt++) bf[nt] = *(const short8*)&Bs[(wn*32+nt*16+l16)*200 + kb + g*8];
#pragma unroll
    for (int mt=0;mt<2;mt++)
#pragma unroll
      for (int nt=0;nt<2;nt++)
        acc[mt][nt] = mfma32(af[mt], bf[nt], acc[mt][nt]);
  }
#pragma unroll
  for (int nt=0;nt<2;nt++){
    int n = wn*32 + nt*16 + l16;
    if (n < 48){
      int c = n>>3, kpq = n&7;
      float bias = tb2s[c];
#pragma unroll
      for (int mt=0;mt<2;mt++){
        int mb = m0 + wm*32 + mt*16 + g*4;
#pragma unroll
        for (int reg=0;reg<4;reg++){
          int m = mb + reg;
          int b = m / V1; int v24 = m - b*V1;
          int y24 = v24/(S1*S1), x24=(v24/S1)%S1, z24=v24%S1;
          int vox = (2*y24+((kpq>>2)&1))*(S0*S0) + (2*x24+((kpq>>1)&1))*S0 + 2*z24+(kpq&1);
          size_t oi = (size_t)(b*C0+c)*V0 + vox;
          out[oi] = acc[mt][nt][reg] + bias + skipp[oi];
        }
      }
    }
  }
}

// ------------- fused stem LN over 768 (in-place bf16): z=0 q(rope,scale) z=1 k(rope) z=2 v -------------
__global__ __launch_bounds__(256) void ln768_stem_kernel(
    unsigned short* __restrict__ qb, unsigned short* __restrict__ kb2,
    unsigned short* __restrict__ vb,
    const float* __restrict__ qg, const float* __restrict__ qbi,
    const float* __restrict__ kg, const float* __restrict__ kbi,
    const float* __restrict__ vg, const float* __restrict__ vbi, float qscale){
  int z = blockIdx.y;
  unsigned short* buf = (z==0)?qb:((z==1)?kb2:vb);
  const float* g  = (z==0)?qg:((z==1)?kg:vg);
  const float* bia= (z==0)?qbi:((z==1)?kbi:vbi);
  float scale = (z==0)? qscale : 1.0f;
  int tok = blockIdx.x*4 + (threadIdx.x>>6), lane = threadIdx.x&63;
  unsigned short* row = buf + (size_t)tok*C2;
  float v[12]; float s1=0.f,s2=0.f;
#pragma unroll
  for (int i=0;i<12;i++){ float t=bf2f(row[i*64+lane]); v[i]=t; s1+=t; s2+=t*t; }
#pragma unroll
  for (int off=32;off>0;off>>=1){ s1+=__shfl_xor(s1,off); s2+=__shfl_xor(s2,off); }
  float u=s1*(1.f/C2);
  float inv=rsqrtf(s2*(1.f/C2)-u*u+1e-6f);
  if (z==2){
#pragma unroll
    for (int i=0;i<12;i++){ int j=i*64+lane; row[j]=f2bf((v[i]-u)*inv*g[j]+bia[j]); }
  } else {
    int pos = tok % LL;
#pragma unroll
    for (int i=0;i<6;i++){
      int j=i*64+lane;
      float xn1=(v[i]-u)*inv*g[j]+bia[j];
      float xn2=(v[i+6]-u)*inv*g[j+384]+bia[j+384];
      float fr=(float)pos*__expf(-0.02398526139f*(float)j);  // 10000^{-j/384}
      float cs=cosf(fr), sn=sinf(fr);
      row[j]     = f2bf((xn1*cs - xn2*sn)*scale);
      row[j+384] = f2bf((xn2*cs + xn1*sn)*scale);
    }
  }
}

// ------------- V transpose, LDS-tiled: vbf [m][768] -> vT [(b*12+h)*64+d][1728] -------------
__global__ __launch_bounds__(256) void vtrans_kernel(const unsigned short* __restrict__ vbf,
    unsigned short* __restrict__ vT){
  __shared__ unsigned short T[64*72];
  int tok0 = blockIdx.x*64;
  int h = blockIdx.y, b = blockIdx.z;
  int t = threadIdx.x;
#pragma unroll
  for (int i=0;i<2;i++){
    int idx = t + i*256;
    int token = idx>>3, dc = idx&7;
    uint4 d4 = *(const uint4*)&vbf[(size_t)(b*LL+tok0+token)*C2 + h*64 + dc*8];
    const unsigned short* s = (const unsigned short*)&d4;
#pragma unroll
    for (int j2=0;j2<8;j2++) T[(dc*8+j2)*72 + token] = s[j2];
  }
  __syncthreads();
  int r = t>>2, seg = t&3;
  unsigned short* dst = vT + (size_t)((b*NH+h)*HD + r)*LL + tok0 + seg*16;
  uint4 o[2];
  unsigned short* os = (unsigned short*)o;
#pragma unroll
  for (int j2=0;j2<16;j2++) os[j2] = T[r*72 + seg*16 + j2];
  *(uint4*)dst = o[0];
  *(uint4*)(dst+8) = o[1];
}

// ---------------- transposed MFMA flash attention, split-K x4, raw exp2, XCD-swizzled ----------------
// 3 q-row-groups per wave; 3-deep LDS ring + counted vmcnt (loads stay in flight across
// barriers, T3/T4) + s_setprio around the compute cluster (T5).
__global__ __launch_bounds__(256) void attn_kernel(const unsigned short* __restrict__ q,
    const unsigned short* __restrict__ k, const unsigned short* __restrict__ vt,
    unsigned short* __restrict__ opart, float* __restrict__ lbuf){
  __shared__ __align__(16) unsigned char smem[49152];
  unsigned short* Ks = (unsigned short*)smem;       // per buf: [64 keys][64 d] chunk-swizzled
  unsigned short* Vs = Ks + 4096;                   // per buf: [64 d][64 keys]; buf stride 8192 shorts
  int flat = blockIdx.x;                  // grid 864 = 8*108 exact
  int xcd = flat & 7, slot = flat >> 3;
  int tile = xcd*108 + slot;
  int h = tile / 72; int rem = tile - h*72;
  int zb = rem / 9, qt = rem - zb*9;
  int b = zb >> 2, split = zb & 3;
  int t=threadIdx.x, w=t>>6, lane=t&63;
  int g=lane>>4, l16=lane&15;
  short8 qA[3], qB[3];
#pragma unroll
  for (int j=0;j<3;j++){
    const unsigned short* qrow = q + (size_t)(b*LL + qt*192 + w*48 + j*16 + l16)*C2 + h*64;
    qA[j] = *(const short8*)(qrow + g*8);
    qB[j] = *(const short8*)(qrow + 32 + g*8);
  }
  const unsigned short* kbase = k + (size_t)(b*LL)*C2 + h*64;
  const unsigned short* vbase = vt + (size_t)((b*NH+h)*HD)*LL;
  int sub = lane>>3;
  int chs = (lane&7) ^ sub;
  int ktb = split*7, kte = (split==3)? 27 : (split*7+7);
  const unsigned short* gptr[4];
  unsigned short* ldst[4];
  int gstep[4];
#pragma unroll
  for (int cc=0;cc<4;cc++){
    int ii = w*4+cc;
    if (ii<8){
      int key = ktb*64 + ii*8 + sub;
      gptr[cc] = kbase + (size_t)key*C2 + chs*8;
      gstep[cc] = 64*C2;
      ldst[cc] = &Ks[ii*512];
    } else {
      int d = (ii-8)*8 + sub;
      gptr[cc] = vbase + (size_t)d*LL + ktb*64 + chs*8;
      gstep[cc] = 64;
      ldst[cc] = &Vs[(ii-8)*512];
    }
  }
  int sw = l16 & 7;
  const unsigned short* ksrow = &Ks[l16*64 + (g^sw)*8];
  int c2d = (((4+g)^sw) - (g^sw))*8;
  const unsigned short* vsrow = &Vs[l16*64 + (g&1)*4];
  int xk[4];
#pragma unroll
  for (int kc=0;kc<4;kc++) xk[kc] = (((kc*2 + (g>>1)) ^ sw))*8;
  short4v vones;
  vones[0]=vones[1]=vones[2]=vones[3]=(short)0x3F80;  // bf16 1.0 x4
  float4v O4[3][4] = {};
  float4v Ol[3] = {};
  auto STAGE = [&](int buf){
    int so = buf*8192;
#pragma unroll
    for (int cc=0;cc<4;cc++){
      load_lds16(gptr[cc], ldst[cc]+so);
      gptr[cc] += gstep[cc];
    }
  };
  auto COMPUTE = [&](int buf){
    int co = buf*8192;
    const unsigned short* kr = ksrow + co;
    const unsigned short* vr = vsrow + co;
    float4v sc[3][4];
    __builtin_amdgcn_s_setprio(1);
#pragma unroll
    for (int nt=0;nt<4;nt++){
      short8 k1 = *(const short8*)(kr + nt*1024);
      short8 k2 = *(const short8*)(kr + nt*1024 + c2d);
#pragma unroll
      for (int j=0;j<3;j++){
        float4v zz = {};
        zz = mfma32(k1, qA[j], zz);
        zz = mfma32(k2, qB[j], zz);
        sc[j][nt] = zz;
      }
    }
#pragma unroll
    for (int j=0;j<3;j++)
#pragma unroll
      for (int nt=0;nt<4;nt++)
#pragma unroll
        for (int reg=0;reg<4;reg++)
          sc[j][nt][reg] = exp2v(sc[j][nt][reg]);
    short4v pbs[3][4];
#pragma unroll
    for (int j=0;j<3;j++)
#pragma unroll
      for (int kc=0;kc<4;kc++){
        union { short4v v; unsigned int u[2]; } pb;
        pb.u[0] = pk_bf16(sc[j][kc][0], sc[j][kc][1]);
        pb.u[1] = pk_bf16(sc[j][kc][2], sc[j][kc][3]);
        pbs[j][kc] = pb.v;
      }
#pragma unroll
    for (int kc=0;kc<4;kc++){
      const unsigned short* vp = vr + xk[kc];
      short4v va[4];
#pragma unroll
      for (int dt=0;dt<4;dt++) va[dt] = *(const short4v*)(vp + dt*1024);
#pragma unroll
      for (int j=0;j<3;j++){
        Ol[j] = mfma16(vones, pbs[j][kc], Ol[j]);
#pragma unroll
        for (int dt=0;dt<4;dt++)
          O4[j][dt] = mfma16(va[dt], pbs[j][kc], O4[j][dt]);
      }
    }
    __builtin_amdgcn_s_setprio(0);
  };
  const int NTK = kte - ktb;   // 7 (splits 0-2) or 6 (split 3), block-uniform
  STAGE(0); STAGE(1);
  asm volatile("s_waitcnt vmcnt(4)" ::: "memory");   // buf0 landed; buf1's 4 in flight
  __builtin_amdgcn_s_barrier();
  __builtin_amdgcn_sched_barrier(0);
  int cur = 0;
  for (int tt=0; tt<NTK-2; tt++){
    int nb = cur+2; if (nb>=3) nb-=3;
    STAGE(nb);
    COMPUTE(cur);
    asm volatile("s_waitcnt vmcnt(4)" ::: "memory"); // tile tt+1 landed; tt+2 in flight
    __builtin_amdgcn_s_barrier();
    __builtin_amdgcn_sched_barrier(0);
    cur++; if (cur>=3) cur-=3;
  }
  COMPUTE(cur);
  asm volatile("s_waitcnt vmcnt(0)" ::: "memory");
  __builtin_amdgcn_s_barrier();
  __builtin_amdgcn_sched_barrier(0);
  cur++; if (cur>=3) cur-=3;
  COMPUTE(cur);
  __syncthreads();                      // all LDS reads done before smem reuse
  float* Ot = (float*)smem;
  float* ot = Ot + w*1216;            // stride 76 floats (2-way bank alias, free)
  int qq = lane>>2, c4 = lane&3;
#pragma unroll
  for (int j=0;j<3;j++){
#pragma unroll
    for (int dt=0;dt<4;dt++)
      *(float4*)&ot[l16*76 + dt*16 + g*4] =
          make_float4(O4[j][dt][0],O4[j][dt][1],O4[j][dt][2],O4[j][dt][3]);
    if (g==0){
      int qi = qt*192 + w*48 + j*16 + l16;
      lbuf[((size_t)(b*4+split)*NH+h)*LL + qi] = Ol[j][0];
    }
    unsigned short* orow = opart + (size_t)split*MDIM*C2
                + (size_t)(b*LL + qt*192 + w*48 + j*16 + qq)*C2 + h*64;
#pragma unroll
    for (int p=0;p<4;p++){
      float4 vv = *(float4*)&ot[qq*76 + p*16 + c4*4];
      uint2 pk; pk.x = pk_bf16(vv.x,vv.y); pk.y = pk_bf16(vv.z,vv.w);
      *(uint2*)&orow[p*16 + c4*4] = pk;
    }
    __syncthreads();
  }
}

// ---------------- combine 4 splits + post-attn LN -> aob K-BLOCKED [m/128][k/32][128][32] ----------------
__global__ __launch_bounds__(256) void attn_post_kernel(const unsigned short* __restrict__ opart,
    const float* __restrict__ lbuf,
    const float* __restrict__ g, const float* __restrict__ bia,
    unsigned short* __restrict__ aob){
  int t=threadIdx.x, w=t>>6, lane=t&63;
  int m = blockIdx.x*4 + w;               // grid 864
  int b = m / LL, l = m - b*LL;
  const unsigned short* o0 = opart + (size_t)m*C2;
  unsigned short* ob2 = aob + ((size_t)(m>>7)*24)*4096 + (size_t)(m&127)*32
                        + (lane&31) + (size_t)(lane>>5)*4096;
  float vv[12]; float s1=0.f, s2=0.f;
#pragma unroll
  for (int i=0;i<12;i++){
    float ls = 0.f;
#pragma unroll
    for (int s=0;s<4;s++) ls += lbuf[((size_t)(b*4+s)*NH+i)*LL + l];
    float inv = 1.f/ls;
    int j = i*64+lane;
    float val = 0.f;
#pragma unroll
    for (int s=0;s<4;s++) val += bf2f(o0[(size_t)s*MDIM*C2 + j]);
    val *= inv;
    vv[i]=val; s1+=val; s2+=val*val;
  }
#pragma unroll
  for (int off=32;off>0;off>>=1){ s1+=__shfl_xor(s1,off); s2+=__shfl_xor(s2,off); }
  float u=s1*(1.f/C2);
  float invs=rsqrtf(s2*(1.f/C2)-u*u+1e-6f);
#pragma unroll
  for (int i=0;i<12;i++){
    int cj = lane*NH + i;                 // permuted gamma: channel p=h*64+d -> c=d*12+h
    ob2[(size_t)i*8192] = f2bf((vv[i]-u)*invs*g[cj]+bia[cj]);   // jblk = i*2 + (lane>>5)
  }
}

extern "C" void kernel_launch(void* const* d_in, const int* in_sizes, int n_in,
                              void* d_out, int out_size, void* d_ws, size_t ws_size,
                              hipStream_t stream){
  (void)in_sizes; (void)n_in; (void)out_size; (void)ws_size;
  const float* x    =(const float*)d_in[0];
  const float* skip =(const float*)d_in[1];
  const float* q_w1 =(const float*)d_in[2];
  const float* q_g1 =(const float*)d_in[3];
  const float* q_b1 =(const float*)d_in[4];
  const float* q_w2 =(const float*)d_in[5];
  const float* q_g2 =(const float*)d_in[6];
  const float* q_b2 =(const float*)d_in[7];
  const float* k_w1 =(const float*)d_in[8];
  const float* k_g1 =(const float*)d_in[9];
  const float* k_b1 =(const float*)d_in[10];
  const float* k_w2 =(const float*)d_in[11];
  const float* k_g2 =(const float*)d_in[12];
  const float* k_b2 =(const float*)d_in[13];
  const float* v_w1 =(const float*)d_in[14];
  const float* v_g1 =(const float*)d_in[15];
  const float* v_b1 =(const float*)d_in[16];
  const float* v_w2 =(const float*)d_in[17];
  const float* v_g2 =(const float*)d_in[18];
  const float* v_b2 =(const float*)d_in[19];
  const float* o_tw1=(const float*)d_in[20];
  const float* o_g  =(const float*)d_in[21];
  const float* o_b  =(const float*)d_in[22];
  const float* o_tw2=(const float*)d_in[23];
  const float* o_tb2=(const float*)d_in[24];
  const float* ns_w =(const float*)d_in[25];
  const float* ns_b =(const float*)d_in[26];
  const float* nx_w =(const float*)d_in[27];
  const float* nx_b =(const float*)d_in[28];
  const float* no_w =(const float*)d_in[29];
  const float* no_b =(const float*)d_in[30];
  float* out=(float*)d_out;

  char* W = (char*)d_ws;
  unsigned short* lnSb = (unsigned short*)(W + 0);          //  2,654,208
  unsigned short* lnXb = (unsigned short*)(W + 2654208);    //  2,654,208
  unsigned short* h1q  = (unsigned short*)(W + 5308416);    // 10,616,832
  unsigned short* h1k  = (unsigned short*)(W + 15925248);   // 10,616,832
  unsigned short* h1v  = (unsigned short*)(W + 26542080);   // 10,616,832
  unsigned short* w2tq = (unsigned short*)(W + 37158912);   //  2,359,296
  unsigned short* w2tk = (unsigned short*)(W + 39518208);   //  2,359,296
  unsigned short* w2tv = (unsigned short*)(W + 41877504);   //  2,359,296
  unsigned short* qbf  = (unsigned short*)(W + 44236800);   //  5,308,416
  unsigned short* kbf  = (unsigned short*)(W + 49545216);   //  5,308,416
  unsigned short* vbf  = (unsigned short*)(W + 54853632);   //  5,308,416
  unsigned short* vT   = (unsigned short*)(W + 60162048);   //  5,308,416
  unsigned short* aob  = (unsigned short*)(W + 65470464);   //  5,308,416
  unsigned short* Btd  = (unsigned short*)(W + 70778880);   //  2,359,296
  unsigned short* Bt48 = (unsigned short*)(W + 73138176);   //     24,576
  unsigned short* w1q  = (unsigned short*)(W + 73162752);   //     18,432
  unsigned short* w1k  = (unsigned short*)(W + 73181184);   //     18,432
  unsigned short* w1v  = (unsigned short*)(W + 73199616);   //     18,432 -> end 73,218,048
  // overlays:
  float* lbuf  = (float*)(W + 0);                     // 663,552 (lnSb dead after conv1)
  unsigned short* opart = (unsigned short*)(W + 5308416);  // 4x5,308,416 bf16 (h1q+h1k dead)
  unsigned short* dh   = (unsigned short*)(W + 5308416);   // 10,616,832 bf16 (opart dead after attn_post)

  const float QSCALE = 0.125f*1.44269504089f;  // 1/sqrt(64) * log2(e)

  prep_kernel<<<20316,256,0,stream>>>(skip, x, ns_w, ns_b, nx_w, nx_b, lnSb, lnXb,
      q_w2,k_w2,v_w2,o_tw1,o_tw2, q_w1,k_w1,v_w1,
      w2tq,w2tk,w2tv,Btd,Bt48, w1q,w1k,w1v);
  conv1_kernel<<<dim3(432,1,3),256,0,stream>>>(lnSb,lnXb, w1q,w1k,w1v,
      q_g1,q_b1, k_g1,k_b1, v_g1,v_b1, h1q,h1k,h1v);
  gemm_stem_kernel<<<976,256,0,stream>>>(h1q,h1k,h1v,
      w2tq,w2tk,w2tv, qbf,kbf,vbf);
  ln768_stem_kernel<<<dim3(864,3),256,0,stream>>>(qbf,kbf,vbf,
      q_g2,q_b2, k_g2,k_b2, v_g2,v_b2, QSCALE);
  vtrans_kernel<<<dim3(27,12,2),256,0,stream>>>(vbf, vT);
  attn_kernel<<<864,256,0,stream>>>(qbf, kbf, vT, opart, lbuf);
  attn_post_kernel<<<864,256,0,stream>>>(opart, lbuf, no_w, no_b, aob);
  gemm_debed_kernel<<<648,256,0,stream>>>(aob, Btd, dh);
  final_kernel<<<432,256,0,stream>>>(dh, Bt48, o_g, o_b, o_tb2, skip, out);
}

// Round 9
// 306.676 us; speedup vs baseline: 1.0208x; 1.0208x over previous
//
#include <hip/hip_runtime.h>
#include <math.h>

#define BB_ 2
#define C0 6
#define S0 48
#define V0 (S0*S0*S0)      // 110592
#define C1 192
#define S1 24
#define V1 (S1*S1*S1)      // 13824
#define C2 768
#define S2 12
#define LL (S2*S2*S2)      // 1728
#define NH 12
#define HD 64
#define KDIM (C1*8)        // 1536
#define MDIM (BB_*LL)      // 3456

typedef __attribute__((ext_vector_type(8))) short short8;
typedef __attribute__((ext_vector_type(4))) short short4v;
typedef __attribute__((ext_vector_type(4))) float float4v;

static __device__ __forceinline__ float gelu_exact(float x){
  return 0.5f*x*(1.0f+erff(x*0.70710678118654752440f));
}
static __device__ __forceinline__ unsigned short f2bf(float f){
  unsigned int u = __float_as_uint(f);
  unsigned int r = (u + 0x7fffu + ((u>>16)&1u)) >> 16;
  return (unsigned short)r;
}
static __device__ __forceinline__ unsigned int pk_bf16(float a, float b){
#if __has_builtin(__builtin_amdgcn_cvt_pk_bf16_f32)
  typedef __attribute__((ext_vector_type(2))) __bf16 bf2;
  bf2 r = __builtin_amdgcn_cvt_pk_bf16_f32(a,b);
  union { bf2 v; unsigned int u; } cv; cv.v = r;
  return cv.u;
#else
  return (unsigned int)f2bf(a) | ((unsigned int)f2bf(b)<<16);
#endif
}
static __device__ __forceinline__ float bf2f(unsigned short u){
  return __uint_as_float(((unsigned int)u)<<16);
}
static __device__ __forceinline__ float exp2v(float x){
#if __has_builtin(__builtin_amdgcn_exp2f)
  return __builtin_amdgcn_exp2f(x);
#else
  return exp2f(x);
#endif
}
static __device__ __forceinline__ void load_lds16(const void* g, void* l){
  __builtin_amdgcn_global_load_lds((const __attribute__((address_space(1))) unsigned int*)g,
      (__attribute__((address_space(3))) unsigned int*)l, 16, 0, 0);
}
static __device__ __forceinline__ float4v mfma32(short8 a, short8 b, float4v c){
  return __builtin_amdgcn_mfma_f32_16x16x32_bf16(a,b,c,0,0,0);
}
static __device__ __forceinline__ float4v mfma16(short4v a, short4v b, float4v c){
#if __has_builtin(__builtin_amdgcn_mfma_f32_16x16x16bf16_1k)
  return __builtin_amdgcn_mfma_f32_16x16x16bf16_1k(a,b,c,0,0,0);
#else
  asm volatile("v_mfma_f32_16x16x16_bf16 %0, %1, %2, %0" : "+v"(c) : "v"(a), "v"(b));
  return c;
#endif
}

// A matrices for the big GEMMs are stored K-BLOCKED: [m/128][k/32][128][32] (8KB tiles)
// B matrices: [n/64][k/32][64][32] (4KB tiles) -> staging reads are CONTIGUOUS (DRAM-friendly).

// ---------------- prep: LN6 (skip,x) + all weight repacks, one launch ----------------
__global__ __launch_bounds__(256) void prep_kernel(
    const float* __restrict__ skin, const float* __restrict__ xin,
    const float* __restrict__ nsw, const float* __restrict__ nsb,
    const float* __restrict__ nxw, const float* __restrict__ nxb,
    unsigned short* __restrict__ outS, unsigned short* __restrict__ outX,
    const float* __restrict__ qw2, const float* __restrict__ kw2, const float* __restrict__ vw2,
    const float* __restrict__ tw1, const float* __restrict__ tw2,
    const float* __restrict__ qw1, const float* __restrict__ kw1, const float* __restrict__ vw1,
    unsigned short* __restrict__ w2tq, unsigned short* __restrict__ w2tk,
    unsigned short* __restrict__ w2tv, unsigned short* __restrict__ Btd,
    unsigned short* __restrict__ Bt48,
    unsigned short* __restrict__ w1q, unsigned short* __restrict__ w1k,
    unsigned short* __restrict__ w1v){
  int bx = blockIdx.x;
  if (bx < 1728){                         // LN over 6 channels (channels_first)
    int z = bx >= 864;
    const float* in = z ? xin : skin;
    const float* w  = z ? nxw : nsw;
    const float* bi = z ? nxb : nsb;
    unsigned short* out = z ? outX : outS;
    int idx = (bx - z*864)*256 + threadIdx.x;
    int b = idx / V0, vox = idx - b*V0;
    const float* p = in + (size_t)b*(C0*V0) + vox;
    float v[C0]; float s=0.f;
#pragma unroll
    for (int c=0;c<C0;c++){ v[c]=p[(size_t)c*V0]; s+=v[c]; }
    float u = s*(1.f/C0);
    float ss=0.f;
#pragma unroll
    for (int c=0;c<C0;c++){ float d=v[c]-u; ss+=d*d; }
    float inv = rsqrtf(ss*(1.f/C0)+1e-6f);
    unsigned short* o = out + (size_t)b*(C0*V0) + vox;
#pragma unroll
    for (int c=0;c<C0;c++) o[(size_t)c*V0] = f2bf((v[c]-u)*inv*w[c]+bi[c]);
    return;
  }
  bx -= 1728;
  if (bx < 13824){                       // 3 x 4608 : w2 repacks -> blocked [oc/64][k/32][64][32]
    int z = bx/4608;
    int idx = (bx - z*4608)*256 + threadIdx.x;
    const float* w2 = (z==0)?qw2:((z==1)?kw2:vw2);
    unsigned short* o = (z==0)?w2tq:((z==1)?w2tk:w2tv);
    int oc = idx/KDIM; int k = idx-oc*KDIM; int p = k/C1; int ic = k-p*C1;
    size_t dst = ((size_t)(oc>>6)*48 + (k>>5))*2048 + (oc&63)*32 + (k&31);
    o[dst] = f2bf(w2[(size_t)oc*KDIM + ic*8 + p]);
  } else if (bx < 18432){                // tw1 -> blocked [n/64][k/32][64][32] (k=p head-major)
    int idx = (bx-13824)*256 + threadIdx.x;
    int n = idx/C2; int p = idx-n*C2;
    int i = ((p&63)*NH) + (p>>6);
    int kpq = n/C1, o2 = n-kpq*C1;
    size_t dst = ((size_t)(n>>6)*24 + (p>>5))*2048 + (n&63)*32 + (p&31);
    Btd[dst] = f2bf(tw1[(size_t)i*KDIM + o2*8 + kpq]);
  } else if (bx < 18480){                // 48 blocks: tw2 -> [n=c*8+kpq pad64][i]
    int idx = (bx-18432)*256 + threadIdx.x;
    int n = idx/C1; int i = idx-n*C1;
    Bt48[idx] = (n<48) ? f2bf(tw2[(size_t)i*48 + n]) : (unsigned short)0;
  } else {                               // 108 blocks: w1 -> bf16 passthrough
    int idx = (bx-18480)*256 + threadIdx.x;  // 27648 = 3*9216
    int z = idx / 9216; int r = idx - z*9216;
    const float* w1 = (z==0)?qw1:((z==1)?kw1:vw1);
    unsigned short* o = (z==0)?w1q:((z==1)?w1k:w1v);
    o[r] = f2bf(w1[r]);
  }
}

// ------------- conv1 via MFMA, one tile-job per wave; blocked output via LDS transpose -------------
__global__ __launch_bounds__(256) void conv1_kernel(
    const unsigned short* __restrict__ lnSb, const unsigned short* __restrict__ lnXb,
    const unsigned short* __restrict__ w1bq, const unsigned short* __restrict__ w1bk,
    const unsigned short* __restrict__ w1bv,
    const float* __restrict__ qg1, const float* __restrict__ qb1,
    const float* __restrict__ kg1, const float* __restrict__ kb1,
    const float* __restrict__ vg1, const float* __restrict__ vb1,
    unsigned short* __restrict__ h1q, unsigned short* __restrict__ h1k,
    unsigned short* __restrict__ h1v){
  __shared__ __align__(16) unsigned short Ost[4][16*200];   // 25.6 KB, padded vs bank conflict
  int z = blockIdx.z;
  const unsigned short* in = (z==0)? lnSb : lnXb;
  const unsigned short* Wb = (z==0)?w1bq:((z==1)?w1bk:w1bv);
  const float* g1 = (z==0)?qg1:((z==1)?kg1:vg1);
  const float* b1 = (z==0)?qb1:((z==1)?kb1:vb1);
  unsigned short* h1p = (z==0)?h1q:((z==1)?h1k:h1v);
  int t = threadIdx.x, w = t>>6, lane = t&63;
  int g = lane>>4, l16 = lane&15;
  int j = blockIdx.x*4 + w;
  int bxh = j/18, mt = j - bxh*18;
  int b = bxh/48; int rem = bxh - b*48; int y = rem>>1, xh = rem&1;
  int xo = mt/3, zo = mt - xo*3;
  int xv = xh*12 + xo*2 + (l16>>3);
  int zv = zo*8 + (l16&7);
  int x2 = 2*xv, z2 = 2*zv, y2 = 2*y;
  const unsigned short* base = in + (size_t)b*C0*V0;
  union { short8 v; unsigned int u[4]; } aA;     // k=g*8+jj  -> ic=g, p=jj
  {
    size_t rb = (size_t)g*V0;
    aA.u[0] = *(const unsigned int*)&base[rb + (y2+0)*(S0*S0) + (x2+0)*S0 + z2];
    aA.u[1] = *(const unsigned int*)&base[rb + (y2+0)*(S0*S0) + (x2+1)*S0 + z2];
    aA.u[2] = *(const unsigned int*)&base[rb + (y2+1)*(S0*S0) + (x2+0)*S0 + z2];
    aA.u[3] = *(const unsigned int*)&base[rb + (y2+1)*(S0*S0) + (x2+1)*S0 + z2];
  }
  union { short4v v; unsigned int u[2]; } aB;    // k=32+g*4+jj -> ic=4+(g>>1), p=(g&1)*4+jj
  {
    size_t rb = (size_t)(4+(g>>1))*V0 + (y2+(g&1))*(S0*S0);
    aB.u[0] = *(const unsigned int*)&base[rb + (x2+0)*S0 + z2];
    aB.u[1] = *(const unsigned int*)&base[rb + (x2+1)*S0 + z2];
  }
  float4v acc[12];
#pragma unroll
  for (int ot=0; ot<12; ot++){
    short8  wA = *(const short8*)&Wb[(ot*16+l16)*48 + g*8];
    short4v wB = *(const short4v*)&Wb[(ot*16+l16)*48 + 32 + g*4];
    float4v a = {};
    a = mfma32(wA, aA.v, a);
    a = mfma16(wB, aB.v, a);
    acc[ot] = a;
  }
  float s1=0.f, s2=0.f;
#pragma unroll
  for (int ot=0;ot<12;ot++)
#pragma unroll
    for (int reg=0;reg<4;reg++){ float v=acc[ot][reg]; s1+=v; s2+=v*v; }
  s1 += __shfl_xor(s1,16); s1 += __shfl_xor(s1,32);
  s2 += __shfl_xor(s2,16); s2 += __shfl_xor(s2,32);
  float u = s1*(1.f/C1);
  float inv = rsqrtf(s2*(1.f/C1)-u*u+1e-6f);
  // token geometry: tok = tokbase + t2, t2=(l16&7)>>1 (4 consecutive, 4-aligned)
  int tokbase = (y>>1)*(S2*S2) + (xh*6+xo)*S2 + zo*4;
  int m0_ = b*LL + tokbase;
  int panel = m0_>>7, row0 = m0_&127;
  int Y4 = (y&1)*4;
  int p8x = (l16>>3)*2 + (l16&1);     // p8 = Y4 + p8x
  int t2 = (l16&7)>>1;
  unsigned short* Lw = &Ost[w][(p8x*4+t2)*200];
#pragma unroll
  for (int ot=0; ot<12; ot++){
    int oc0 = ot*16 + g*4;
    float4 gg = *(const float4*)&g1[oc0];
    float4 bb = *(const float4*)&b1[oc0];
    float x0 = gelu_exact((acc[ot][0]-u)*inv*gg.x+bb.x);
    float x1 = gelu_exact((acc[ot][1]-u)*inv*gg.y+bb.y);
    float x2e= gelu_exact((acc[ot][2]-u)*inv*gg.z+bb.z);
    float x3 = gelu_exact((acc[ot][3]-u)*inv*gg.w+bb.w);
    uint2 pk; pk.x = pk_bf16(x0,x1); pk.y = pk_bf16(x2e,x3);
    *(uint2*)&Lw[oc0] = pk;
  }
  __syncthreads();
  // write out: chunk c = p8x*6 + ocr (24 chunks/wave), each 4 rows x 32 k = 256B contiguous
  unsigned short* pb2 = h1p + ((size_t)panel*48 + Y4*6)*4096 + row0*32;
#pragma unroll
  for (int it=0; it<6; it++){
    int flat = it*64 + lane;
    int c = flat>>4, s = flat&15;          // c in 0..23, s in 0..15
    int pp = c/6, ocr = c - pp*6;
    uint4 d = *(const uint4*)&Ost[w][(pp*4 + (s>>2))*200 + ocr*32 + (s&3)*8];
    *(uint4*)&pb2[(size_t)c*4096 + (s>>2)*32 + (s&3)*8] = d;
  }
}

// ---------------- fused stem GEMM, 128x64 tiles, 3-ring counted vmcnt, CONTIGUOUS tiles ----------------
__global__ __launch_bounds__(256) void gemm_stem_kernel(
    const unsigned short* __restrict__ A0, const unsigned short* __restrict__ A1,
    const unsigned short* __restrict__ A2,
    const unsigned short* __restrict__ B0, const unsigned short* __restrict__ B1,
    const unsigned short* __restrict__ B2,
    unsigned short* __restrict__ Cq, unsigned short* __restrict__ Ck,
    unsigned short* __restrict__ Cv){
  int flat = blockIdx.x;
  int xcd = flat & 7, slot = flat >> 3;
  int tile = xcd*122 + slot;
  if (tile >= 972) return;
  int z = tile/324; int rr = tile - z*324;
  int mp = rr/12, np = rr - mp*12;
  const unsigned short* A = (z==0)?A0:((z==1)?A1:A2);
  const unsigned short* Bt = (z==0)?B0:((z==1)?B1:B2);
  unsigned short* Cp = (z==0)?Cq:((z==1)?Ck:Cv);
  __shared__ __align__(16) unsigned short Al[3][4096];
  __shared__ __align__(16) unsigned short Bl[3][2048];
  int t=threadIdx.x, w=t>>6, lane=t&63;
  int g=lane>>4, l16=lane&15;
  int wm=w>>1, wn=w&1;
  int loff = (lane>>2)*32 + (((lane&3) ^ ((lane>>3)&3))<<3);
  int crd  = (g ^ ((l16>>1)&3))*8;
  const unsigned short* gp[3];
  unsigned short* ld[3];
  int step[3];
#pragma unroll
  for (int cc=0;cc<3;cc++){
    int ch = w*3+cc;
    if (ch<8){
      gp[cc] = A + ((size_t)mp*48)*4096 + ch*512 + loff;
      step[cc] = 4096; ld[cc] = &Al[0][ch*512];
    } else {
      gp[cc] = Bt + ((size_t)np*48)*2048 + (ch-8)*512 + loff;
      step[cc] = 2048; ld[cc] = &Bl[0][(ch-8)*512];
    }
  }
  auto STAGE = [&](int buf){
#pragma unroll
    for (int cc=0;cc<3;cc++){
      load_lds16(gp[cc], ld[cc] + buf*step[cc]);
      gp[cc] += step[cc];
    }
  };
  float4v acc[4][2] = {};
  auto COMPUTE = [&](int buf){
    short8 af[4], bf[2];
#pragma unroll
    for (int mt=0;mt<4;mt++) af[mt] = *(const short8*)&Al[buf][(wm*64+mt*16+l16)*32 + crd];
#pragma unroll
    for (int nt=0;nt<2;nt++) bf[nt] = *(const short8*)&Bl[buf][(wn*32+nt*16+l16)*32 + crd];
#pragma unroll
    for (int mt=0;mt<4;mt++)
#pragma unroll
      for (int nt=0;nt<2;nt++)
        acc[mt][nt] = mfma32(af[mt], bf[nt], acc[mt][nt]);
  };
  const int NT = 48;
  STAGE(0); STAGE(1);
  asm volatile("s_waitcnt vmcnt(3)" ::: "memory");
  __builtin_amdgcn_s_barrier();
  __builtin_amdgcn_sched_barrier(0);
  int cur = 0;
  for (int tt=0; tt<NT-2; tt++){
    int nb = cur+2; if (nb>=3) nb-=3;
    STAGE(nb);
    COMPUTE(cur);
    asm volatile("s_waitcnt vmcnt(3)" ::: "memory");   // tile tt+1 landed; tt+2 in flight
    __builtin_amdgcn_s_barrier();
    __builtin_amdgcn_sched_barrier(0);
    cur++; if (cur>=3) cur-=3;
  }
  COMPUTE(cur);
  asm volatile("s_waitcnt vmcnt(0)" ::: "memory");
  __builtin_amdgcn_s_barrier();
  __builtin_amdgcn_sched_barrier(0);
  cur++; if (cur>=3) cur-=3;
  COMPUTE(cur);
  int m0 = mp*128, n0 = np*64;
#pragma unroll
  for (int mt=0;mt<4;mt++){
    int mb = m0 + wm*64 + mt*16 + g*4;
#pragma unroll
    for (int nt=0;nt<2;nt++){
      int col = n0 + wn*32 + nt*16 + l16;
#pragma unroll
      for (int reg=0;reg<4;reg++)
        Cp[(size_t)(mb+reg)*C2 + col] = f2bf(acc[mt][nt][reg]);
    }
  }
}

// ---------------- debed GEMM: 128x64 tiles, 3-ring counted vmcnt, CONTIGUOUS tiles ----------------
__global__ __launch_bounds__(256) void gemm_debed_kernel(const unsigned short* __restrict__ A,
    const unsigned short* __restrict__ Bt, unsigned short* __restrict__ C){
  int flat = blockIdx.x;
  int xcd = flat & 7, slot = flat >> 3;
  int tile = xcd*81 + slot;
  int mp = tile/24, np = tile - mp*24;
  __shared__ __align__(16) unsigned short Al[3][4096];
  __shared__ __align__(16) unsigned short Bl[3][2048];
  int t=threadIdx.x, w=t>>6, lane=t&63;
  int g=lane>>4, l16=lane&15;
  int wm=w>>1, wn=w&1;
  int loff = (lane>>2)*32 + (((lane&3) ^ ((lane>>3)&3))<<3);
  int crd  = (g ^ ((l16>>1)&3))*8;
  const unsigned short* gp[3];
  unsigned short* ld[3];
  int step[3];
#pragma unroll
  for (int cc=0;cc<3;cc++){
    int ch = w*3+cc;
    if (ch<8){
      gp[cc] = A + ((size_t)mp*24)*4096 + ch*512 + loff;
      step[cc] = 4096; ld[cc] = &Al[0][ch*512];
    } else {
      gp[cc] = Bt + ((size_t)np*24)*2048 + (ch-8)*512 + loff;
      step[cc] = 2048; ld[cc] = &Bl[0][(ch-8)*512];
    }
  }
  auto STAGE = [&](int buf){
#pragma unroll
    for (int cc=0;cc<3;cc++){
      load_lds16(gp[cc], ld[cc] + buf*step[cc]);
      gp[cc] += step[cc];
    }
  };
  float4v acc[4][2] = {};
  auto COMPUTE = [&](int buf){
    short8 af[4], bf[2];
#pragma unroll
    for (int mt=0;mt<4;mt++) af[mt] = *(const short8*)&Al[buf][(wm*64+mt*16+l16)*32 + crd];
#pragma unroll
    for (int nt=0;nt<2;nt++) bf[nt] = *(const short8*)&Bl[buf][(wn*32+nt*16+l16)*32 + crd];
#pragma unroll
    for (int mt=0;mt<4;mt++)
#pragma unroll
      for (int nt=0;nt<2;nt++)
        acc[mt][nt] = mfma32(af[mt], bf[nt], acc[mt][nt]);
  };
  const int NT = 24;
  STAGE(0); STAGE(1);
  asm volatile("s_waitcnt vmcnt(3)" ::: "memory");
  __builtin_amdgcn_s_barrier();
  __builtin_amdgcn_sched_barrier(0);
  int cur = 0;
  for (int tt=0; tt<NT-2; tt++){
    int nb = cur+2; if (nb>=3) nb-=3;
    STAGE(nb);
    COMPUTE(cur);
    asm volatile("s_waitcnt vmcnt(3)" ::: "memory");
    __builtin_amdgcn_s_barrier();
    __builtin_amdgcn_sched_barrier(0);
    cur++; if (cur>=3) cur-=3;
  }
  COMPUTE(cur);
  asm volatile("s_waitcnt vmcnt(0)" ::: "memory");
  __builtin_amdgcn_s_barrier();
  __builtin_amdgcn_sched_barrier(0);
  cur++; if (cur>=3) cur-=3;
  COMPUTE(cur);
  int m0 = mp*128, n0 = np*64;
#pragma unroll
  for (int nt=0;nt<2;nt++){
    int n = n0 + wn*32 + nt*16 + l16;
    int kpq = n / C1;
    int o = n - kpq*C1;
#pragma unroll
    for (int mt=0;mt<4;mt++){
      int mb = m0 + wm*64 + mt*16 + g*4;
#pragma unroll
      for (int reg=0;reg<4;reg++){
        int m = mb + reg;
        int b = m / LL; int tok = m - b*LL;
        int h = tok/(S2*S2), ww=(tok/S2)%S2, d=tok%S2;
        int v24 = (2*h+((kpq>>2)&1))*(S1*S1) + (2*ww+((kpq>>1)&1))*S1 + (2*d+(kpq&1));
        C[(size_t)(b*V1+v24)*C1 + o] = f2bf(acc[mt][nt][reg]);
      }
    }
  }
}

// ---------------- final: LN(192)+GELU fused into convT2 GEMM + bias + residual ----------------
__global__ __launch_bounds__(256) void final_kernel(const unsigned short* __restrict__ dh,
    const unsigned short* __restrict__ Bt48, const float* __restrict__ og,
    const float* __restrict__ ob, const float* __restrict__ tb2s,
    const float* __restrict__ skipp, float* __restrict__ out){
  __shared__ __align__(16) unsigned short As[64*200];
  __shared__ __align__(16) unsigned short Bs[64*200];
  int t=threadIdx.x, w=t>>6, lane=t&63;
  int g=lane>>4, l16=lane&15;
  int m0 = blockIdx.x*64;
  for (int n8 = t; n8 < 1536; n8 += 256){
    int n64 = n8/24, kk = (n8 - n64*24)*8;
    uint4 d4 = *(const uint4*)&Bt48[n64*192 + kk];
    *(uint4*)&Bs[n64*200 + kk] = d4;
  }
  float g0=og[lane], g1v=og[lane+64], g2v=og[lane+128];
  float b0=ob[lane], b1v=ob[lane+64], b2v=ob[lane+128];
  for (int rr=0; rr<16; rr++){
    int rl = w*16 + rr;
    const unsigned short* row = dh + (size_t)(m0+rl)*C1;
    float v0=bf2f(row[lane]), v1=bf2f(row[lane+64]), v2=bf2f(row[lane+128]);
    float s1=v0+v1+v2, s2=v0*v0+v1*v1+v2*v2;
#pragma unroll
    for (int off=32;off>0;off>>=1){ s1+=__shfl_xor(s1,off); s2+=__shfl_xor(s2,off); }
    float u=s1*(1.f/C1), inv=rsqrtf(s2*(1.f/C1)-u*u+1e-6f);
    As[rl*200+lane]     = f2bf(gelu_exact((v0-u)*inv*g0+b0));
    As[rl*200+lane+64]  = f2bf(gelu_exact((v1-u)*inv*g1v+b1v));
    As[rl*200+lane+128] = f2bf(gelu_exact((v2-u)*inv*g2v+b2v));
  }
  __syncthreads();
  int wm=w>>1, wn=w&1;
  float4v acc[2][2] = {};
#pragma unroll
  for (int kb=0;kb<192;kb+=32){
    short8 af[2], bf[2];
#pragma unroll
    for (int mt=0;mt<2;mt++) af[mt] = *(const short8*)&As[(wm*32+mt*16+l16)*200 + kb + g*8];
#pragma unroll
    for (int nt=0;nt<2;nt++) bf[nt] = *(const short8*)&Bs[(wn*32+nt*16+l16)*200 + kb + g*8];
#pragma unroll
    for (int mt=0;mt<2;mt++)
#pragma unroll
      for (int nt=0;nt<2;nt++)
        acc[mt][nt] = mfma32(af[mt], bf[nt], acc[mt][nt]);
  }
#pragma unroll
  for (int nt=0;nt<2;nt++){
    int n = wn*32 + nt*16 + l16;
    if (n < 48){
      int c = n>>3, kpq = n&7;
      float bias = tb2s[c];
#pragma unroll
      for (int mt=0;mt<2;mt++){
        int mb = m0 + wm*32 + mt*16 + g*4;
#pragma unroll
        for (int reg=0;reg<4;reg++){
          int m = mb + reg;
          int b = m / V1; int v24 = m - b*V1;
          int y24 = v24/(S1*S1), x24=(v24/S1)%S1, z24=v24%S1;
          int vox = (2*y24+((kpq>>2)&1))*(S0*S0) + (2*x24+((kpq>>1)&1))*S0 + 2*z24+(kpq&1);
          size_t oi = (size_t)(b*C0+c)*V0 + vox;
          out[oi] = acc[mt][nt][reg] + bias + skipp[oi];
        }
      }
    }
  }
}

// ------------- fused stem LN over 768 (in-place bf16): z=0 q(rope,scale) z=1 k(rope) z=2 v -------------
__global__ __launch_bounds__(256) void ln768_stem_kernel(
    unsigned short* __restrict__ qb, unsigned short* __restrict__ kb2,
    unsigned short* __restrict__ vb,
    const float* __restrict__ qg, const float* __restrict__ qbi,
    const float* __restrict__ kg, const float* __restrict__ kbi,
    const float* __restrict__ vg, const float* __restrict__ vbi, float qscale){
  int z = blockIdx.y;
  unsigned short* buf = (z==0)?qb:((z==1)?kb2:vb);
  const float* g  = (z==0)?qg:((z==1)?kg:vg);
  const float* bia= (z==0)?qbi:((z==1)?kbi:vbi);
  float scale = (z==0)? qscale : 1.0f;
  int tok = blockIdx.x*4 + (threadIdx.x>>6), lane = threadIdx.x&63;
  unsigned short* row = buf + (size_t)tok*C2;
  float v[12]; float s1=0.f,s2=0.f;
#pragma unroll
  for (int i=0;i<12;i++){ float t=bf2f(row[i*64+lane]); v[i]=t; s1+=t; s2+=t*t; }
#pragma unroll
  for (int off=32;off>0;off>>=1){ s1+=__shfl_xor(s1,off); s2+=__shfl_xor(s2,off); }
  float u=s1*(1.f/C2);
  float inv=rsqrtf(s2*(1.f/C2)-u*u+1e-6f);
  if (z==2){
#pragma unroll
    for (int i=0;i<12;i++){ int j=i*64+lane; row[j]=f2bf((v[i]-u)*inv*g[j]+bia[j]); }
  } else {
    int pos = tok % LL;
#pragma unroll
    for (int i=0;i<6;i++){
      int j=i*64+lane;
      float xn1=(v[i]-u)*inv*g[j]+bia[j];
      float xn2=(v[i+6]-u)*inv*g[j+384]+bia[j+384];
      float fr=(float)pos*__expf(-0.02398526139f*(float)j);  // 10000^{-j/384}
      float cs=cosf(fr), sn=sinf(fr);
      row[j]     = f2bf((xn1*cs - xn2*sn)*scale);
      row[j+384] = f2bf((xn2*cs + xn1*sn)*scale);
    }
  }
}

// ------------- V transpose, LDS-tiled: vbf [m][768] -> vT [(b*12+h)*64+d][1728] -------------
__global__ __launch_bounds__(256) void vtrans_kernel(const unsigned short* __restrict__ vbf,
    unsigned short* __restrict__ vT){
  __shared__ unsigned short T[64*72];
  int tok0 = blockIdx.x*64;
  int h = blockIdx.y, b = blockIdx.z;
  int t = threadIdx.x;
#pragma unroll
  for (int i=0;i<2;i++){
    int idx = t + i*256;
    int token = idx>>3, dc = idx&7;
    uint4 d4 = *(const uint4*)&vbf[(size_t)(b*LL+tok0+token)*C2 + h*64 + dc*8];
    const unsigned short* s = (const unsigned short*)&d4;
#pragma unroll
    for (int j2=0;j2<8;j2++) T[(dc*8+j2)*72 + token] = s[j2];
  }
  __syncthreads();
  int r = t>>2, seg = t&3;
  unsigned short* dst = vT + (size_t)((b*NH+h)*HD + r)*LL + tok0 + seg*16;
  uint4 o[2];
  unsigned short* os = (unsigned short*)o;
#pragma unroll
  for (int j2=0;j2<16;j2++) os[j2] = T[r*72 + seg*16 + j2];
  *(uint4*)dst = o[0];
  *(uint4*)(dst+8) = o[1];
}

// ---------------- transposed MFMA flash attention, split-K x4, raw exp2, XCD-swizzled ----------------
// 3 q-row-groups per wave (192 q rows / block); 2-phase dbuf, one barrier per kt.
// (Round-6/7 proven version: 32KB LDS, ~5 blocks/CU; ring/setprio variant regressed — occupancy.)
__global__ __launch_bounds__(256) void attn_kernel(const unsigned short* __restrict__ q,
    const unsigned short* __restrict__ k, const unsigned short* __restrict__ vt,
    unsigned short* __restrict__ opart, float* __restrict__ lbuf){
  __shared__ __align__(16) unsigned char smem[32768];
  unsigned short* Ks = (unsigned short*)smem;       // [buf][64 keys][64 d] chunk-swizzled
  unsigned short* Vs = Ks + 4096;                   // [buf][64 d][64 keys]; buf stride 8192 shorts
  int flat = blockIdx.x;                  // grid 864 = 8*108 exact
  int xcd = flat & 7, slot = flat >> 3;
  int tile = xcd*108 + slot;
  int h = tile / 72; int rem = tile - h*72;
  int zb = rem / 9, qt = rem - zb*9;
  int b = zb >> 2, split = zb & 3;
  int t=threadIdx.x, w=t>>6, lane=t&63;
  int g=lane>>4, l16=lane&15;
  short8 qA[3], qB[3];
#pragma unroll
  for (int j=0;j<3;j++){
    const unsigned short* qrow = q + (size_t)(b*LL + qt*192 + w*48 + j*16 + l16)*C2 + h*64;
    qA[j] = *(const short8*)(qrow + g*8);
    qB[j] = *(const short8*)(qrow + 32 + g*8);
  }
  const unsigned short* kbase = k + (size_t)(b*LL)*C2 + h*64;
  const unsigned short* vbase = vt + (size_t)((b*NH+h)*HD)*LL;
  int sub = lane>>3;
  int chs = (lane&7) ^ sub;
  int ktb = split*7, kte = (split==3)? 27 : (split*7+7);
  const unsigned short* gptr[4];
  unsigned short* ldst[4];
  int gstep[4];
#pragma unroll
  for (int cc=0;cc<4;cc++){
    int ii = w*4+cc;
    if (ii<8){
      int key = ktb*64 + ii*8 + sub;
      gptr[cc] = kbase + (size_t)key*C2 + chs*8;
      gstep[cc] = 64*C2;
      ldst[cc] = &Ks[ii*512];
    } else {
      int d = (ii-8)*8 + sub;
      gptr[cc] = vbase + (size_t)d*LL + ktb*64 + chs*8;
      gstep[cc] = 64;
      ldst[cc] = &Vs[(ii-8)*512];
    }
  }
  int sw = l16 & 7;
  const unsigned short* ksrow = &Ks[l16*64 + (g^sw)*8];
  int c2d = (((4+g)^sw) - (g^sw))*8;
  const unsigned short* vsrow = &Vs[l16*64 + (g&1)*4];
  int xk[4];
#pragma unroll
  for (int kc=0;kc<4;kc++) xk[kc] = (((kc*2 + (g>>1)) ^ sw))*8;
  short4v vones;
  vones[0]=vones[1]=vones[2]=vones[3]=(short)0x3F80;  // bf16 1.0 x4
  float4v O4[3][4] = {};
  float4v Ol[3] = {};
#pragma unroll
  for (int cc=0;cc<4;cc++){
    load_lds16(gptr[cc], ldst[cc]);
    gptr[cc] += gstep[cc];
  }
  __syncthreads();
  int cur = 0;
  for (int kt=ktb; kt<kte; kt++){
    if (kt+1 < kte){
      int so = (cur^1)*8192;
#pragma unroll
      for (int cc=0;cc<4;cc++){
        load_lds16(gptr[cc], ldst[cc]+so);
        gptr[cc] += gstep[cc];
      }
    }
    int co = cur*8192;
    const unsigned short* kr = ksrow + co;
    const unsigned short* vr = vsrow + co;
    float4v sc[3][4];
#pragma unroll
    for (int nt=0;nt<4;nt++){
      short8 k1 = *(const short8*)(kr + nt*1024);
      short8 k2 = *(const short8*)(kr + nt*1024 + c2d);
#pragma unroll
      for (int j=0;j<3;j++){
        float4v zz = {};
        zz = mfma32(k1, qA[j], zz);
        zz = mfma32(k2, qB[j], zz);
        sc[j][nt] = zz;
      }
    }
#pragma unroll
    for (int j=0;j<3;j++)
#pragma unroll
      for (int nt=0;nt<4;nt++)
#pragma unroll
        for (int reg=0;reg<4;reg++)
          sc[j][nt][reg] = exp2v(sc[j][nt][reg]);
    short4v pbs[3][4];
#pragma unroll
    for (int j=0;j<3;j++)
#pragma unroll
      for (int kc=0;kc<4;kc++){
        union { short4v v; unsigned int u[2]; } pb;
        pb.u[0] = pk_bf16(sc[j][kc][0], sc[j][kc][1]);
        pb.u[1] = pk_bf16(sc[j][kc][2], sc[j][kc][3]);
        pbs[j][kc] = pb.v;
      }
#pragma unroll
    for (int kc=0;kc<4;kc++){
      const unsigned short* vp = vr + xk[kc];
      short4v va[4];
#pragma unroll
      for (int dt=0;dt<4;dt++) va[dt] = *(const short4v*)(vp + dt*1024);
#pragma unroll
      for (int j=0;j<3;j++){
        Ol[j] = mfma16(vones, pbs[j][kc], Ol[j]);
#pragma unroll
        for (int dt=0;dt<4;dt++)
          O4[j][dt] = mfma16(va[dt], pbs[j][kc], O4[j][dt]);
      }
    }
    __syncthreads();
    cur ^= 1;
  }
  float* Ot = (float*)smem;
  float* ot = Ot + w*1216;            // stride 76 floats (2-way bank alias, free)
  int qq = lane>>2, c4 = lane&3;
#pragma unroll
  for (int j=0;j<3;j++){
#pragma unroll
    for (int dt=0;dt<4;dt++)
      *(float4*)&ot[l16*76 + dt*16 + g*4] =
          make_float4(O4[j][dt][0],O4[j][dt][1],O4[j][dt][2],O4[j][dt][3]);
    if (g==0){
      int qi = qt*192 + w*48 + j*16 + l16;
      lbuf[((size_t)(b*4+split)*NH+h)*LL + qi] = Ol[j][0];
    }
    unsigned short* orow = opart + (size_t)split*MDIM*C2
                + (size_t)(b*LL + qt*192 + w*48 + j*16 + qq)*C2 + h*64;
#pragma unroll
    for (int p=0;p<4;p++){
      float4 vv = *(float4*)&ot[qq*76 + p*16 + c4*4];
      uint2 pk; pk.x = pk_bf16(vv.x,vv.y); pk.y = pk_bf16(vv.z,vv.w);
      *(uint2*)&orow[p*16 + c4*4] = pk;
    }
    __syncthreads();
  }
}

// ---------------- combine 4 splits + post-attn LN -> aob K-BLOCKED [m/128][k/32][128][32] ----------------
__global__ __launch_bounds__(256) void attn_post_kernel(const unsigned short* __restrict__ opart,
    const float* __restrict__ lbuf,
    const float* __restrict__ g, const float* __restrict__ bia,
    unsigned short* __restrict__ aob){
  int t=threadIdx.x, w=t>>6, lane=t&63;
  int m = blockIdx.x*4 + w;               // grid 864
  int b = m / LL, l = m - b*LL;
  const unsigned short* o0 = opart + (size_t)m*C2;
  unsigned short* ob2 = aob + ((size_t)(m>>7)*24)*4096 + (size_t)(m&127)*32
                        + (lane&31) + (size_t)(lane>>5)*4096;
  float vv[12]; float s1=0.f, s2=0.f;
#pragma unroll
  for (int i=0;i<12;i++){
    float ls = 0.f;
#pragma unroll
    for (int s=0;s<4;s++) ls += lbuf[((size_t)(b*4+s)*NH+i)*LL + l];
    float inv = 1.f/ls;
    int j = i*64+lane;
    float val = 0.f;
#pragma unroll
    for (int s=0;s<4;s++) val += bf2f(o0[(size_t)s*MDIM*C2 + j]);
    val *= inv;
    vv[i]=val; s1+=val; s2+=val*val;
  }
#pragma unroll
  for (int off=32;off>0;off>>=1){ s1+=__shfl_xor(s1,off); s2+=__shfl_xor(s2,off); }
  float u=s1*(1.f/C2);
  float invs=rsqrtf(s2*(1.f/C2)-u*u+1e-6f);
#pragma unroll
  for (int i=0;i<12;i++){
    int cj = lane*NH + i;                 // permuted gamma: channel p=h*64+d -> c=d*12+h
    ob2[(size_t)i*8192] = f2bf((vv[i]-u)*invs*g[cj]+bia[cj]);   // jblk = i*2 + (lane>>5)
  }
}

extern "C" void kernel_launch(void* const* d_in, const int* in_sizes, int n_in,
                              void* d_out, int out_size, void* d_ws, size_t ws_size,
                              hipStream_t stream){
  (void)in_sizes; (void)n_in; (void)out_size; (void)ws_size;
  const float* x    =(const float*)d_in[0];
  const float* skip =(const float*)d_in[1];
  const float* q_w1 =(const float*)d_in[2];
  const float* q_g1 =(const float*)d_in[3];
  const float* q_b1 =(const float*)d_in[4];
  const float* q_w2 =(const float*)d_in[5];
  const float* q_g2 =(const float*)d_in[6];
  const float* q_b2 =(const float*)d_in[7];
  const float* k_w1 =(const float*)d_in[8];
  const float* k_g1 =(const float*)d_in[9];
  const float* k_b1 =(const float*)d_in[10];
  const float* k_w2 =(const float*)d_in[11];
  const float* k_g2 =(const float*)d_in[12];
  const float* k_b2 =(const float*)d_in[13];
  const float* v_w1 =(const float*)d_in[14];
  const float* v_g1 =(const float*)d_in[15];
  const float* v_b1 =(const float*)d_in[16];
  const float* v_w2 =(const float*)d_in[17];
  const float* v_g2 =(const float*)d_in[18];
  const float* v_b2 =(const float*)d_in[19];
  const float* o_tw1=(const float*)d_in[20];
  const float* o_g  =(const float*)d_in[21];
  const float* o_b  =(const float*)d_in[22];
  const float* o_tw2=(const float*)d_in[23];
  const float* o_tb2=(const float*)d_in[24];
  const float* ns_w =(const float*)d_in[25];
  const float* ns_b =(const float*)d_in[26];
  const float* nx_w =(const float*)d_in[27];
  const float* nx_b =(const float*)d_in[28];
  const float* no_w =(const float*)d_in[29];
  const float* no_b =(const float*)d_in[30];
  float* out=(float*)d_out;

  char* W = (char*)d_ws;
  unsigned short* lnSb = (unsigned short*)(W + 0);          //  2,654,208
  unsigned short* lnXb = (unsigned short*)(W + 2654208);    //  2,654,208
  unsigned short* h1q  = (unsigned short*)(W + 5308416);    // 10,616,832
  unsigned short* h1k  = (unsigned short*)(W + 15925248);   // 10,616,832
  unsigned short* h1v  = (unsigned short*)(W + 26542080);   // 10,616,832
  unsigned short* w2tq = (unsigned short*)(W + 37158912);   //  2,359,296
  unsigned short* w2tk = (unsigned short*)(W + 39518208);   //  2,359,296
  unsigned short* w2tv = (unsigned short*)(W + 41877504);   //  2,359,296
  unsigned short* qbf  = (unsigned short*)(W + 44236800);   //  5,308,416
  unsigned short* kbf  = (unsigned short*)(W + 49545216);   //  5,308,416
  unsigned short* vbf  = (unsigned short*)(W + 54853632);   //  5,308,416
  unsigned short* vT   = (unsigned short*)(W + 60162048);   //  5,308,416
  unsigned short* aob  = (unsigned short*)(W + 65470464);   //  5,308,416
  unsigned short* Btd  = (unsigned short*)(W + 70778880);   //  2,359,296
  unsigned short* Bt48 = (unsigned short*)(W + 73138176);   //     24,576
  unsigned short* w1q  = (unsigned short*)(W + 73162752);   //     18,432
  unsigned short* w1k  = (unsigned short*)(W + 73181184);   //     18,432
  unsigned short* w1v  = (unsigned short*)(W + 73199616);   //     18,432 -> end 73,218,048
  // overlays:
  float* lbuf  = (float*)(W + 0);                     // 663,552 (lnSb dead after conv1)
  unsigned short* opart = (unsigned short*)(W + 5308416);  // 4x5,308,416 bf16 (h1q+h1k dead)
  unsigned short* dh   = (unsigned short*)(W + 5308416);   // 10,616,832 bf16 (opart dead after attn_post)

  const float QSCALE = 0.125f*1.44269504089f;  // 1/sqrt(64) * log2(e)

  prep_kernel<<<20316,256,0,stream>>>(skip, x, ns_w, ns_b, nx_w, nx_b, lnSb, lnXb,
      q_w2,k_w2,v_w2,o_tw1,o_tw2, q_w1,k_w1,v_w1,
      w2tq,w2tk,w2tv,Btd,Bt48, w1q,w1k,w1v);
  conv1_kernel<<<dim3(432,1,3),256,0,stream>>>(lnSb,lnXb, w1q,w1k,w1v,
      q_g1,q_b1, k_g1,k_b1, v_g1,v_b1, h1q,h1k,h1v);
  gemm_stem_kernel<<<976,256,0,stream>>>(h1q,h1k,h1v,
      w2tq,w2tk,w2tv, qbf,kbf,vbf);
  ln768_stem_kernel<<<dim3(864,3),256,0,stream>>>(qbf,kbf,vbf,
      q_g2,q_b2, k_g2,k_b2, v_g2,v_b2, QSCALE);
  vtrans_kernel<<<dim3(27,12,2),256,0,stream>>>(vbf, vT);
  attn_kernel<<<864,256,0,stream>>>(qbf, kbf, vT, opart, lbuf);
  attn_post_kernel<<<864,256,0,stream>>>(opart, lbuf, no_w, no_b, aob);
  gemm_debed_kernel<<<648,256,0,stream>>>(aob, Btd, dh);
  final_kernel<<<432,256,0,stream>>>(dh, Bt48, o_g, o_b, o_tb2, skip, out);
}